// Round 2
// baseline (221.252 us; speedup 1.0000x reference)
//
#include <hip/hip_runtime.h>
#include <hip/hip_cooperative_groups.h>
#include <stdint.h>
#include <float.h>

namespace cg = cooperative_groups;

#define BLK 256
#define IPT 8                 // owner points per thread (8 independent min-chains)
#define OWNERS (BLK * IPT)    // 2048 owners per work unit
#define SLICE 128             // scanned points per work unit (2 KB LDS)
#define SUB 64                // subtile granularity for deferred-index recovery

typedef unsigned long long ull;

// Monotone float -> uint transform (preserves <, total order) and inverse.
__device__ __forceinline__ unsigned int ford(float f) {
    int b = __float_as_int(f);
    return (b >= 0) ? ((unsigned)b ^ 0x80000000u) : ~(unsigned)b;
}
__device__ __forceinline__ float ford_inv(unsigned int u) {
    int b = (u & 0x80000000u) ? (int)(u ^ 0x80000000u) : (int)~u;
    return __int_as_float(b);
}

// Single cooperative dispatch:
//   phase 0: init mins (agent-scope stores) + zero out      -> grid.sync
//   phase 1: min-value scan (identical arithmetic to the verified kernel;
//            per-64-pt subtile base tracking, u64 atomicMin merge)
//                                                           -> grid.sync
//   phase 2: branchless bit-exact index recovery + normal dot + reduction
// Eliminates 2 hipMemsetAsync dispatches + 1 kernel dispatch + 3 stream gaps.
__global__ __launch_bounds__(BLK) void fused(
    const float* __restrict__ p, const float* __restrict__ g,
    const float* __restrict__ pn, const float* __restrict__ gn,
    ull* __restrict__ mins, float* __restrict__ out, int N, int M)
{
    cg::grid_group grid = cg::this_grid();
    const int gsize = gridDim.x * BLK;
    const int gtid = blockIdx.x * BLK + threadIdx.x;
    const int tot = N + M;

    // ---- phase 0: init (coherent-point stores; no memset dispatches) ----
    for (int t = gtid; t < tot; t += gsize)
        __hip_atomic_store(&mins[t], ~0ull, __ATOMIC_RELAXED, __HIP_MEMORY_SCOPE_AGENT);
    if (gtid == 0)
        __hip_atomic_store(out, 0.0f, __ATOMIC_RELAXED, __HIP_MEMORY_SCOPE_AGENT);
    grid.sync();

    // ---- phase 1: min VALUE only, deferred-index ----
    const int rowSlices = M / SLICE;
    const int colSlices = N / SLICE;
    const int rowWU = (N / OWNERS) * rowSlices;   // 4*256  = 1024
    const int colWU = (M / OWNERS) * colSlices;   // 16*64  = 1024
    const int totWU = rowWU + colWU;              // 2048

    __shared__ float4 sb[SLICE];

    for (int wu = blockIdx.x; wu < totWU; wu += gridDim.x) {
        const float* A; const float* B; ull* outm; int id, nSlices;
        if (wu < rowWU) { id = wu;         A = p; B = g; outm = mins;     nSlices = rowSlices; }
        else            { id = wu - rowWU; A = g; B = p; outm = mins + N; nSlices = colSlices; }
        const int chunk = id / nSlices;
        const int slice = id - chunk * nSlices;
        const int s0 = slice * SLICE;

        __syncthreads();   // protect sb against readers from previous work unit

        // Stage slice (coords + |B|^2). Explicit fmaf: recovery recomputes the
        // identical expression so bit-exact equality holds.
        if (threadIdx.x < SLICE) {
            int s = s0 + threadIdx.x;
            float bx = B[3 * s], by = B[3 * s + 1], bz = B[3 * s + 2];
            float w = fmaf(bz, bz, fmaf(by, by, bx * bx));
            sb[threadIdx.x] = make_float4(bx, by, bz, w);
        }

        const int o0 = chunk * OWNERS + threadIdx.x;
        float ax[IPT], ay[IPT], az[IPT], best[IPT];
        int base[IPT];
#pragma unroll
        for (int r = 0; r < IPT; ++r) {
            int o = o0 + r * BLK;
            ax[r] = -2.0f * A[3 * o];
            ay[r] = -2.0f * A[3 * o + 1];
            az[r] = -2.0f * A[3 * o + 2];
            best[r] = FLT_MAX;
            base[r] = s0;
        }
        __syncthreads();

        for (int st = 0; st < SLICE; st += SUB) {
            float prev[IPT];
#pragma unroll
            for (int r = 0; r < IPT; ++r) prev[r] = best[r];
#pragma unroll 2
            for (int k = st; k < st + SUB; k += 2) {
                float4 q0 = sb[k];        // wave-uniform broadcast reads
                float4 q1 = sb[k + 1];
#pragma unroll
                for (int r = 0; r < IPT; ++r) {
                    float v0 = fmaf(ax[r], q0.x, fmaf(ay[r], q0.y, fmaf(az[r], q0.z, q0.w)));
                    float v1 = fmaf(ax[r], q1.x, fmaf(ay[r], q1.y, fmaf(az[r], q1.z, q1.w)));
                    best[r] = fminf(fminf(v0, v1), best[r]);   // -> v_min3_f32
                }
            }
#pragma unroll
            for (int r = 0; r < IPT; ++r)
                if (best[r] < prev[r]) base[r] = s0 + st;   // strict <: first subtile wins
        }

#pragma unroll
        for (int r = 0; r < IPT; ++r) {
            ull packed = ((ull)ford(best[r]) << 32) | (unsigned)base[r];
            atomicMin(&outm[o0 + r * BLK], packed);
        }
    }

    grid.sync();

    // ---- phase 2: branchless bit-exact recovery + normal loss ----
    const float invN = 1.0f / (float)N;   // N, M powers of 2 -> exact
    const float invM = 1.0f / (float)M;
    float c = 0.0f;

    for (int t = gtid; t < tot; t += gsize) {
        const float* A; const float* B; const float* An; const float* Bn;
        int o; float inv;
        if (t < N) { o = t;     A = p; B = g; An = pn; Bn = gn; inv = invN; }
        else       { o = t - N; A = g; B = p; An = gn; Bn = pn; inv = invM; }

        ull packed = __hip_atomic_load(&mins[t], __ATOMIC_RELAXED, __HIP_MEMORY_SCOPE_AGENT);
        float ax = -2.0f * A[3 * o];
        float ay = -2.0f * A[3 * o + 1];
        float az = -2.0f * A[3 * o + 2];
        float bestf = ford_inv((unsigned int)(packed >> 32));
        int b0 = (int)(packed & 0xffffffffull);

        // Branchless first-match: loads stay pipelined (no dependent break).
        int idx = 0x7fffffff;
#pragma unroll 4
        for (int j = 0; j < SUB; ++j) {
            int s = b0 + j;
            float bx = B[3 * s], by = B[3 * s + 1], bz = B[3 * s + 2];
            float w = fmaf(bz, bz, fmaf(by, by, bx * bx));
            float v = fmaf(ax, bx, fmaf(ay, by, fmaf(az, bz, w)));
            int cand = (v == bestf) ? s : 0x7fffffff;
            idx = (cand < idx) ? cand : idx;      // ascending j -> first match = min s
        }
        if (idx == 0x7fffffff) idx = b0;          // defensive; cannot trigger

        float d = An[3 * o] * Bn[3 * idx] + An[3 * o + 1] * Bn[3 * idx + 1]
                + An[3 * o + 2] * Bn[3 * idx + 2];
        c += (1.0f - d) * inv;
    }

#pragma unroll
    for (int off = 32; off > 0; off >>= 1) c += __shfl_down(c, off, 64);
    __shared__ float partial[BLK / 64];
    if ((threadIdx.x & 63) == 0) partial[threadIdx.x >> 6] = c;
    __syncthreads();
    if (threadIdx.x == 0) {
        float s = 0.0f;
#pragma unroll
        for (int w = 0; w < BLK / 64; ++w) s += partial[w];
        if (s != 0.0f) atomicAdd(out, s);   // skipping exact-zero adds never changes the sum
    }
}

extern "C" void kernel_launch(void* const* d_in, const int* in_sizes, int n_in,
                              void* d_out, int out_size, void* d_ws, size_t ws_size,
                              hipStream_t stream) {
    const float* p  = (const float*)d_in[0];   // [N,3] predicted points
    const float* pn = (const float*)d_in[1];   // [N,3] predicted normals (unit)
    const float* g  = (const float*)d_in[2];   // [M,3] gt points
    const float* gn = (const float*)d_in[3];   // [M,3] gt normals (unit)
    const int N = in_sizes[0] / 3;             // 8192
    const int M = in_sizes[2] / 3;             // 32768

    ull* mins = (ull*)d_ws;                    // [N + M]
    float* out = (float*)d_out;

    // One-time co-residency sizing (host-side queries only; graph-capture safe).
    static int gridBlocks = 0;
    if (gridBlocks == 0) {
        int occ = 0, numCU = 0;
        hipOccupancyMaxActiveBlocksPerMultiprocessor(&occ, (const void*)fused, BLK, 0);
        hipDeviceGetAttribute(&numCU, hipDeviceAttributeMultiprocessorCount, 0);
        int mb = occ * numCU;                  // expected 8 * 256 = 2048
        if (mb < 64) mb = 64;
        gridBlocks = mb > 2048 ? 2048 : mb;    // 2048 work units; grid-stride covers rest
    }

    void* args[] = { (void*)&p, (void*)&g, (void*)&pn, (void*)&gn,
                     (void*)&mins, (void*)&out, (void*)&N, (void*)&M };
    hipLaunchCooperativeKernel((const void*)fused, dim3(gridBlocks), dim3(BLK),
                               args, 0, stream);
}

// Round 3
// 122.390 us; speedup vs baseline: 1.8078x; 1.8078x over previous
//
#include <hip/hip_runtime.h>
#include <stdint.h>
#include <float.h>

#define BLK 256
#define IPT 8                  // owner points per thread (8 independent min-chains)
#define OWNERS (BLK * IPT)     // 2048 owners per block
#define SLICE2 256             // scanned points per block, primary path (4 KB LDS)
#define SLICE1 128             // scanned points per block, legacy path
#define SUB 64                 // subtile granularity for deferred-index recovery

typedef unsigned long long ull;

// Monotone float -> uint transform (preserves <, total order) and inverse.
__device__ __forceinline__ unsigned int ford(float f) {
    int b = __float_as_int(f);
    return (b >= 0) ? ((unsigned)b ^ 0x80000000u) : ~(unsigned)b;
}
__device__ __forceinline__ float ford_inv(unsigned int u) {
    int b = (u & 0x80000000u) ? (int)(u ^ 0x80000000u) : (int)~u;
    return __int_as_float(b);
}

// ======================= primary path: 2 dispatches =======================
// Phase 1: each block owns a UNIQUE (chunk, slice-group) pair and writes its
// per-owner partial min to a private ws slot with a PLAIN STORE — no memset
// (every slot is written), no atomics, no sync. Inner loop is bit-identical
// to the verified kernel. packed = ford(best)<<32 | subtile_base; bases ascend
// with slot index, so a plain u64 min over slots == the old atomicMin
// first-occurrence tie rule.
__global__ __launch_bounds__(BLK) void nn_slices(
    const float* __restrict__ p, const float* __restrict__ g,
    ull* __restrict__ wsR, ull* __restrict__ wsC,
    float* __restrict__ out, int N, int M)
{
    __shared__ float4 sb[SLICE2];

    if (blockIdx.x == 0 && threadIdx.x == 0) *out = 0.0f;  // fold memset(out)

    const int rowBlocks = (N / OWNERS) * (M / SLICE2);     // 4*128 = 512
    const float* A; const float* B; ull* ws; int id, nSlices, NO;
    if ((int)blockIdx.x < rowBlocks) {
        id = blockIdx.x;             A = p; B = g; ws = wsR; nSlices = M / SLICE2; NO = N;
    } else {
        id = blockIdx.x - rowBlocks; A = g; B = p; ws = wsC; nSlices = N / SLICE2; NO = M;
    }
    const int chunk = id / nSlices;
    const int j = id - chunk * nSlices;
    const int s0 = j * SLICE2;

    // Stage slice (coords + |B|^2). Explicit fmaf: recovery recomputes the
    // identical expression so bit-exact equality holds.
    {
        int s = s0 + threadIdx.x;
        float bx = B[3 * s], by = B[3 * s + 1], bz = B[3 * s + 2];
        float w = fmaf(bz, bz, fmaf(by, by, bx * bx));
        sb[threadIdx.x] = make_float4(bx, by, bz, w);
    }

    const int o0 = chunk * OWNERS + threadIdx.x;
    float ax[IPT], ay[IPT], az[IPT], best[IPT];
    int base[IPT];
#pragma unroll
    for (int r = 0; r < IPT; ++r) {
        int o = o0 + r * BLK;
        ax[r] = -2.0f * A[3 * o];
        ay[r] = -2.0f * A[3 * o + 1];
        az[r] = -2.0f * A[3 * o + 2];
        best[r] = FLT_MAX;
        base[r] = s0;
    }
    __syncthreads();

    for (int st = 0; st < SLICE2; st += SUB) {
        float prev[IPT];
#pragma unroll
        for (int r = 0; r < IPT; ++r) prev[r] = best[r];
#pragma unroll 2
        for (int k = st; k < st + SUB; k += 2) {
            float4 q0 = sb[k];        // wave-uniform broadcast reads
            float4 q1 = sb[k + 1];
#pragma unroll
            for (int r = 0; r < IPT; ++r) {
                float v0 = fmaf(ax[r], q0.x, fmaf(ay[r], q0.y, fmaf(az[r], q0.z, q0.w)));
                float v1 = fmaf(ax[r], q1.x, fmaf(ay[r], q1.y, fmaf(az[r], q1.z, q1.w)));
                best[r] = fminf(fminf(v0, v1), best[r]);   // -> v_min3_f32
            }
        }
#pragma unroll
        for (int r = 0; r < IPT; ++r)
            if (best[r] < prev[r]) base[r] = s0 + st;   // strict <: first subtile wins
    }

    ull* dst = ws + (size_t)j * NO;   // coalesced: consecutive threads -> consecutive u64
#pragma unroll
    for (int r = 0; r < IPT; ++r)
        dst[o0 + r * BLK] = ((ull)ford(best[r]) << 32) | (unsigned)base[r];
}

// Phase 2: lane-per-owner. Coalesced K-way u64 min over the owner's slots,
// then the verified branchless bit-exact 64-pt rescan, normal dot, and a
// block-level reduction (one atomicAdd per block).
__global__ __launch_bounds__(BLK) void reduce_fin(
    const ull* __restrict__ wsR, const ull* __restrict__ wsC,
    const float* __restrict__ p, const float* __restrict__ g,
    const float* __restrict__ pn, const float* __restrict__ gn,
    float* __restrict__ out, int N, int M, float invN, float invM)
{
    int t = blockIdx.x * BLK + threadIdx.x;
    float c = 0.0f;
    if (t < N + M) {
        const float* A; const float* B; const float* An; const float* Bn;
        const ull* ws; int o, K, NO; float inv;
        if (t < N) { o = t;     A = p; B = g; An = pn; Bn = gn; ws = wsR; K = M / SLICE2; NO = N; inv = invN; }
        else       { o = t - N; A = g; B = p; An = gn; Bn = pn; ws = wsC; K = N / SLICE2; NO = M; inv = invM; }

        ull bestp = ws[o];                       // slot j=0
#pragma unroll 4
        for (int jj = 1; jj < K; ++jj) {         // coalesced across lanes
            ull v2 = ws[(size_t)jj * NO + o];
            bestp = (v2 < bestp) ? v2 : bestp;   // equal ford -> smaller base -> first occurrence
        }

        float ax = -2.0f * A[3 * o];
        float ay = -2.0f * A[3 * o + 1];
        float az = -2.0f * A[3 * o + 2];
        float bestf = ford_inv((unsigned int)(bestp >> 32));
        int b0 = (int)(bestp & 0xffffffffull);

        // Branchless first-match: loads stay pipelined (no dependent break).
        int idx = 0x7fffffff;
#pragma unroll 4
        for (int jj = 0; jj < SUB; ++jj) {
            int s = b0 + jj;
            float bx = B[3 * s], by = B[3 * s + 1], bz = B[3 * s + 2];
            float w = fmaf(bz, bz, fmaf(by, by, bx * bx));
            float v = fmaf(ax, bx, fmaf(ay, by, fmaf(az, bz, w)));
            int cand = (v == bestf) ? s : 0x7fffffff;
            idx = (cand < idx) ? cand : idx;     // ascending -> first match = min s
        }
        if (idx == 0x7fffffff) idx = b0;         // defensive; cannot trigger

        float d = An[3 * o] * Bn[3 * idx] + An[3 * o + 1] * Bn[3 * idx + 1]
                + An[3 * o + 2] * Bn[3 * idx + 2];
        c = (1.0f - d) * inv;
    }
#pragma unroll
    for (int off = 32; off > 0; off >>= 1) c += __shfl_down(c, off, 64);
    __shared__ float partial[BLK / 64];
    if ((threadIdx.x & 63) == 0) partial[threadIdx.x >> 6] = c;
    __syncthreads();
    if (threadIdx.x == 0) {
        float s = 0.0f;
#pragma unroll
        for (int w = 0; w < BLK / 64; ++w) s += partial[w];
        atomicAdd(out, s);
    }
}

// ======================= legacy fallback (verified r0/r1 path) =======================
__global__ __launch_bounds__(BLK) void nn_min_dual(
    const float* __restrict__ p, const float* __restrict__ g,
    ull* __restrict__ rowmin, ull* __restrict__ colmin,
    int rowBlocks, int rowSlices, int colSlices)
{
    __shared__ float4 sb[SLICE1];
    const float* A; const float* B; ull* outmin; int id, nSlices;
    if ((int)blockIdx.x < rowBlocks) {
        id = blockIdx.x;             A = p; B = g; outmin = rowmin; nSlices = rowSlices;
    } else {
        id = blockIdx.x - rowBlocks; A = g; B = p; outmin = colmin; nSlices = colSlices;
    }
    const int chunk = id / nSlices;
    const int slice = id - chunk * nSlices;
    const int s0 = slice * SLICE1;
    if (threadIdx.x < SLICE1) {
        int s = s0 + threadIdx.x;
        float bx = B[3 * s], by = B[3 * s + 1], bz = B[3 * s + 2];
        float w = fmaf(bz, bz, fmaf(by, by, bx * bx));
        sb[threadIdx.x] = make_float4(bx, by, bz, w);
    }
    const int o0 = chunk * OWNERS + threadIdx.x;
    float ax[IPT], ay[IPT], az[IPT], best[IPT];
    int base[IPT];
#pragma unroll
    for (int r = 0; r < IPT; ++r) {
        int o = o0 + r * BLK;
        ax[r] = -2.0f * A[3 * o]; ay[r] = -2.0f * A[3 * o + 1]; az[r] = -2.0f * A[3 * o + 2];
        best[r] = FLT_MAX; base[r] = s0;
    }
    __syncthreads();
    for (int st = 0; st < SLICE1; st += SUB) {
        float prev[IPT];
#pragma unroll
        for (int r = 0; r < IPT; ++r) prev[r] = best[r];
#pragma unroll 2
        for (int k = st; k < st + SUB; k += 2) {
            float4 q0 = sb[k]; float4 q1 = sb[k + 1];
#pragma unroll
            for (int r = 0; r < IPT; ++r) {
                float v0 = fmaf(ax[r], q0.x, fmaf(ay[r], q0.y, fmaf(az[r], q0.z, q0.w)));
                float v1 = fmaf(ax[r], q1.x, fmaf(ay[r], q1.y, fmaf(az[r], q1.z, q1.w)));
                best[r] = fminf(fminf(v0, v1), best[r]);
            }
        }
#pragma unroll
        for (int r = 0; r < IPT; ++r)
            if (best[r] < prev[r]) base[r] = s0 + st;
    }
#pragma unroll
    for (int r = 0; r < IPT; ++r) {
        ull packed = ((ull)ford(best[r]) << 32) | (unsigned)base[r];
        atomicMin(&outmin[o0 + r * BLK], packed);
    }
}

__global__ __launch_bounds__(BLK) void finalize_legacy(
    const ull* __restrict__ rowmin, const ull* __restrict__ colmin,
    const float* __restrict__ p, const float* __restrict__ g,
    const float* __restrict__ pn, const float* __restrict__ gn,
    float* __restrict__ out, int N, int M, float invN, float invM)
{
    int t = blockIdx.x * BLK + threadIdx.x;
    float c = 0.0f;
    if (t < N + M) {
        const float* A; const float* B; const float* An; const float* Bn;
        ull packed; int o; float inv;
        if (t < N) { o = t;     A = p; B = g; An = pn; Bn = gn; packed = rowmin[o]; inv = invN; }
        else       { o = t - N; A = g; B = p; An = gn; Bn = pn; packed = colmin[o]; inv = invM; }
        float ax = -2.0f * A[3 * o], ay = -2.0f * A[3 * o + 1], az = -2.0f * A[3 * o + 2];
        float bestf = ford_inv((unsigned int)(packed >> 32));
        int b0 = (int)(packed & 0xffffffffull);
        int idx = 0x7fffffff;
#pragma unroll 4
        for (int jj = 0; jj < SUB; ++jj) {
            int s = b0 + jj;
            float bx = B[3 * s], by = B[3 * s + 1], bz = B[3 * s + 2];
            float w = fmaf(bz, bz, fmaf(by, by, bx * bx));
            float v = fmaf(ax, bx, fmaf(ay, by, fmaf(az, bz, w)));
            int cand = (v == bestf) ? s : 0x7fffffff;
            idx = (cand < idx) ? cand : idx;
        }
        if (idx == 0x7fffffff) idx = b0;
        float d = An[3 * o] * Bn[3 * idx] + An[3 * o + 1] * Bn[3 * idx + 1]
                + An[3 * o + 2] * Bn[3 * idx + 2];
        c = (1.0f - d) * inv;
    }
#pragma unroll
    for (int off = 32; off > 0; off >>= 1) c += __shfl_down(c, off, 64);
    __shared__ float partial[BLK / 64];
    if ((threadIdx.x & 63) == 0) partial[threadIdx.x >> 6] = c;
    __syncthreads();
    if (threadIdx.x == 0) {
        float s = 0.0f;
#pragma unroll
        for (int w = 0; w < BLK / 64; ++w) s += partial[w];
        atomicAdd(out, s);
    }
}

extern "C" void kernel_launch(void* const* d_in, const int* in_sizes, int n_in,
                              void* d_out, int out_size, void* d_ws, size_t ws_size,
                              hipStream_t stream) {
    const float* p  = (const float*)d_in[0];   // [N,3] predicted points
    const float* pn = (const float*)d_in[1];   // [N,3] predicted normals (unit)
    const float* g  = (const float*)d_in[2];   // [M,3] gt points
    const float* gn = (const float*)d_in[3];   // [M,3] gt normals (unit)
    const int N = in_sizes[0] / 3;             // 8192
    const int M = in_sizes[2] / 3;             // 32768
    float* out = (float*)d_out;

    const size_t needR = (size_t)(M / SLICE2) * N * sizeof(ull);   // 8 MB
    const size_t needC = (size_t)(N / SLICE2) * M * sizeof(ull);   // 8 MB
    const bool geomOK = (N % OWNERS) == 0 && (M % OWNERS) == 0 &&
                        (N % SLICE2) == 0 && (M % SLICE2) == 0 &&
                        ((N + M) % BLK) == 0;

    if (geomOK && ws_size >= needR + needC) {
        // -------- primary: 2 dispatches, no memsets, no atomics in phase 1 --------
        ull* wsR = (ull*)d_ws;
        ull* wsC = wsR + (size_t)(M / SLICE2) * N;
        const int blocks = (N / OWNERS) * (M / SLICE2) + (M / OWNERS) * (N / SLICE2); // 1024
        nn_slices<<<blocks, BLK, 0, stream>>>(p, g, wsR, wsC, out, N, M);
        reduce_fin<<<(N + M) / BLK, BLK, 0, stream>>>(
            wsR, wsC, p, g, pn, gn, out, N, M, 1.0f / N, 1.0f / M);
    } else {
        // -------- legacy verified 4-dispatch path --------
        ull* rowmin = (ull*)d_ws;
        ull* colmin = rowmin + N;
        hipMemsetAsync(d_ws, 0xFF, (size_t)(N + M) * sizeof(ull), stream);
        hipMemsetAsync(d_out, 0, sizeof(float), stream);
        const int rowSlices = M / SLICE1;
        const int colSlices = N / SLICE1;
        const int rowBlocks = (N / OWNERS) * rowSlices;
        const int colBlocks = (M / OWNERS) * colSlices;
        nn_min_dual<<<rowBlocks + colBlocks, BLK, 0, stream>>>(
            p, g, rowmin, colmin, rowBlocks, rowSlices, colSlices);
        int tot = N + M;
        finalize_legacy<<<(tot + BLK - 1) / BLK, BLK, 0, stream>>>(
            rowmin, colmin, p, g, pn, gn, out, N, M, 1.0f / N, 1.0f / M);
    }
}